// Round 1
// baseline (194.411 us; speedup 1.0000x reference)
//
#include <hip/hip_runtime.h>

#define BATCH 4
#define NCLS 2
#define VOX 1638400            // 64*160*160
#define VOX4 (VOX / 4)
#define BLOCKS_X 512
#define THREADS 256
#define NACC 19                // S0, A, n0, P[1..8], N[1..8]
#define NBLOCKS (BLOCKS_X * BATCH)

// ---------------------------------------------------------------------------
// Fused kernel: per-(sample, block) partial reductions + last-block finalize.
// partials layout: [(j*BATCH + b) * BLOCKS_X + blockIdx.x], j in [0,19)
// The LAST block to finish (device-scope ticket) reduces the partials in
// double (identical summation order to the old finalize kernel -> bit-exact)
// and writes the closed-form loss. Counter is re-armed by a 4-byte
// hipMemsetAsync each launch because the workspace is poisoned between runs.
// ---------------------------------------------------------------------------
__global__ __launch_bounds__(THREADS) void blob_fused_kernel(
    const float* __restrict__ x, const int* __restrict__ ml,
    float* __restrict__ partials, unsigned* __restrict__ counter,
    float* __restrict__ out)
{
    const int b = blockIdx.y;
    const float4* __restrict__ x0v = (const float4*)(x + (size_t)b * NCLS * VOX);
    const float4* __restrict__ x1v = (const float4*)(x + (size_t)b * NCLS * VOX + VOX);
    const int4*   __restrict__ mlv = (const int4*)(ml + (size_t)b * VOX);

    float acc[NACC];
#pragma unroll
    for (int j = 0; j < NACC; ++j) acc[j] = 0.f;

    const int stride = BLOCKS_X * THREADS;
    for (int i = blockIdx.x * THREADS + threadIdx.x; i < VOX4; i += stride) {
        float4 a0 = x0v[i];
        float4 a1 = x1v[i];
        int4   m  = mlv[i];
        float xs0[4] = {a0.x, a0.y, a0.z, a0.w};
        float xs1[4] = {a1.x, a1.y, a1.z, a1.w};
        int   ls[4]  = {m.x, m.y, m.z, m.w};
#pragma unroll
        for (int e = 0; e < 4; ++e) {
            // softmax over 2 classes: p0 = 1/(1+exp(x1-x0))
            float p0 = 1.0f / (1.0f + __expf(xs1[e] - xs0[e]));
            int L = ls[e];
            acc[0] += p0;                      // S0
            bool z = (L == 0);
            acc[1] += z ? p0 : 0.f;            // A
            acc[2] += z ? 1.f : 0.f;           // n0
#pragma unroll
            for (int l = 0; l < 8; ++l) {
                bool eq = (L == l + 1);
                acc[3 + l]  += eq ? p0 : 0.f;  // P_l
                acc[11 + l] += eq ? 1.f : 0.f; // N_l
            }
        }
    }

    // block reduce: wave shuffle (64 lanes) -> LDS across 4 waves
    __shared__ float red[4][NACC];
    __shared__ unsigned s_ticket;
    const int lane = threadIdx.x & 63;
    const int wave = threadIdx.x >> 6;
#pragma unroll
    for (int j = 0; j < NACC; ++j) {
        float v = acc[j];
        for (int off = 32; off > 0; off >>= 1) v += __shfl_down(v, off, 64);
        if (lane == 0) red[wave][j] = v;
    }
    __syncthreads();
    if (threadIdx.x < NACC) {
        float s = red[0][threadIdx.x] + red[1][threadIdx.x] +
                  red[2][threadIdx.x] + red[3][threadIdx.x];
        partials[((size_t)threadIdx.x * BATCH + b) * BLOCKS_X + blockIdx.x] = s;
    }

    // ---- last-block-done ticket (device scope) ----
    __syncthreads();                       // partials stores happen-before t0's fence
    if (threadIdx.x == 0) {
        __threadfence();                   // release this block's partials
        s_ticket = __hip_atomic_fetch_add(counter, 1u, __ATOMIC_ACQ_REL,
                                          __HIP_MEMORY_SCOPE_AGENT);
    }
    __syncthreads();
    if (s_ticket != NBLOCKS - 1) return;   // all but the last block retire

    // ---- finalize in the last block (4 waves; arithmetic identical to the
    //      old 512-thread kernel: same per-(j,b) lane-sum + shuffle order) ----
    __shared__ double totals[NACC * BATCH];   // index p = j*BATCH + b
    for (int p = wave; p < NACC * BATCH; p += 4) {
        double s = 0.0;
#pragma unroll
        for (int i = 0; i < BLOCKS_X / 64; ++i)
            s += (double)partials[(size_t)p * BLOCKS_X + lane + i * 64];
        for (int off = 32; off > 0; off >>= 1) s += __shfl_down(s, off, 64);
        if (lane == 0) totals[p] = s;
    }
    __syncthreads();

    if (threadIdx.x == 0) {
        const double Vd = (double)VOX;
        const double TA = 0.3, TB = 0.7;
        double sum_main = 0.0, sum_blob = 0.0;
        for (int bb = 0; bb < BATCH; ++bb) {
            const double S0 = totals[0 * BATCH + bb];
            const double A  = totals[1 * BATCH + bb];
            const double n0 = totals[2 * BATCH + bb];
            // main Tversky, class 0
            {
                double tp = A, fp = S0 - A, fn = n0 - A;
                sum_main += tp / fmax(tp + TA * fp + TB * fn, 1e-8);
            }
            // main Tversky, class 1
            {
                double tp = (Vd - n0) - (S0 - A);
                double fp = (Vd - S0) - tp;
                double fn = (Vd - n0) - tp;
                sum_main += tp / fmax(tp + TA * fp + TB * fn, 1e-8);
            }
            for (int k = 0; k < 8; ++k) {
                const double P0 = totals[(3 + k) * BATCH + bb];
                const double Nl = totals[(11 + k) * BATCH + bb];
                const double P1 = Nl - P0;
                const double mm = Vd - n0 - Nl;  // voxels of OTHER blobs -> p=(.5,.5)
                // class 0: g = (L != lab)
                {
                    double tp = A + 0.5 * mm;
                    double fp = P0;
                    double fn = (Vd - Nl) - tp;
                    sum_blob += tp / fmax(tp + TA * fp + TB * fn, 1e-8);
                }
                // class 1: g = (L == lab)
                {
                    double tp = P1;
                    double fp = (n0 - A) + 0.5 * mm;
                    double fn = P0;
                    sum_blob += tp / fmax(tp + TA * fp + TB * fn, 1e-8);
                }
            }
        }
        // loss = MAIN_W*CRIT_W*main_loss + blob_loss
        //      = -(sum_main / (B*C)) - (0.25/(K*B)) * sum_blob
        out[0] = (float)(-(sum_main / 8.0 + sum_blob / 128.0));
    }
}

extern "C" void kernel_launch(void* const* d_in, const int* in_sizes, int n_in,
                              void* d_out, int out_size, void* d_ws, size_t ws_size,
                              hipStream_t stream) {
    const float* x  = (const float*)d_in[0];
    const int*   ml = (const int*)d_in[1];
    float* out      = (float*)d_out;
    float* partials = (float*)d_ws;   // NACC*BATCH*BLOCKS_X floats = 152 KiB
    unsigned* counter = (unsigned*)((char*)d_ws +
                        (size_t)NACC * BATCH * BLOCKS_X * sizeof(float));

    hipMemsetAsync(counter, 0, sizeof(unsigned), stream);  // re-arm ticket (ws is poisoned)
    dim3 grid(BLOCKS_X, BATCH);
    blob_fused_kernel<<<grid, THREADS, 0, stream>>>(x, ml, partials, counter, out);
}

// Round 2
// 115.112 us; speedup vs baseline: 1.6889x; 1.6889x over previous
//
#include <hip/hip_runtime.h>

#define BATCH 4
#define NCLS 2
#define VOX 1638400            // 64*160*160
#define VOX4 (VOX / 4)
#define BLOCKS_X 320           // 320*256 threads/batch -> exactly 5 iters/thread
#define THREADS 256
#define ITERS (VOX4 / (BLOCKS_X * THREADS))   // = 5, compile-time
#define NACC 19                // S0, A, n0, P[1..8], N[1..8]

// ---------------------------------------------------------------------------
// Kernel 1: per-(sample, block) partial reductions.
// Grid (320,4) = 1280 blocks = exactly 5 blocks/CU; each thread does exactly
// 5 fully-unrolled iterations -> 15 independent 16B loads in flight for
// deep memory pipelining. partials layout: [(j*BATCH+b)*BLOCKS_X + bx] so
// kernel 2's lanes read coalesced along the block axis.
// NOTE: no device-scope fences/atomics here — round-1 showed per-block
// agent-scope release/acquire (buffer_wbl2/buffer_inv) costs ~90 µs.
// ---------------------------------------------------------------------------
__global__ __launch_bounds__(THREADS, 5) void blob_reduce_kernel(
    const float* __restrict__ x, const int* __restrict__ ml,
    float* __restrict__ partials)
{
    const int b = blockIdx.y;
    const float4* __restrict__ x0v = (const float4*)(x + (size_t)b * NCLS * VOX);
    const float4* __restrict__ x1v = (const float4*)(x + (size_t)b * NCLS * VOX + VOX);
    const int4*   __restrict__ mlv = (const int4*)(ml + (size_t)b * VOX);

    float acc[NACC];
#pragma unroll
    for (int j = 0; j < NACC; ++j) acc[j] = 0.f;

    const int tid = blockIdx.x * THREADS + threadIdx.x;   // 0..81919
    const int stride = BLOCKS_X * THREADS;                // 81920

#pragma unroll
    for (int it = 0; it < ITERS; ++it) {
        const int i = tid + it * stride;
        float4 a0 = x0v[i];
        float4 a1 = x1v[i];
        int4   m  = mlv[i];
        float xs0[4] = {a0.x, a0.y, a0.z, a0.w};
        float xs1[4] = {a1.x, a1.y, a1.z, a1.w};
        int   ls[4]  = {m.x, m.y, m.z, m.w};
#pragma unroll
        for (int e = 0; e < 4; ++e) {
            // softmax over 2 classes: p0 = 1/(1+exp(x1-x0))
            float p0 = 1.0f / (1.0f + __expf(xs1[e] - xs0[e]));
            int L = ls[e];
            acc[0] += p0;                      // S0
            bool z = (L == 0);
            acc[1] += z ? p0 : 0.f;            // A
            acc[2] += z ? 1.f : 0.f;           // n0
#pragma unroll
            for (int l = 0; l < 8; ++l) {
                bool eq = (L == l + 1);
                acc[3 + l]  += eq ? p0 : 0.f;  // P_l
                acc[11 + l] += eq ? 1.f : 0.f; // N_l
            }
        }
    }

    // block reduce: wave shuffle (64 lanes) -> LDS across 4 waves
    __shared__ float red[4][NACC];
    const int lane = threadIdx.x & 63;
    const int wave = threadIdx.x >> 6;
#pragma unroll
    for (int j = 0; j < NACC; ++j) {
        float v = acc[j];
        for (int off = 32; off > 0; off >>= 1) v += __shfl_down(v, off, 64);
        if (lane == 0) red[wave][j] = v;
    }
    __syncthreads();
    if (threadIdx.x < NACC) {
        float s = red[0][threadIdx.x] + red[1][threadIdx.x] +
                  red[2][threadIdx.x] + red[3][threadIdx.x];
        partials[((size_t)threadIdx.x * BATCH + b) * BLOCKS_X + blockIdx.x] = s;
    }
}

// ---------------------------------------------------------------------------
// Kernel 2: reduce 320 partials per (j,b) in double, then closed-form loss.
// ---------------------------------------------------------------------------
__global__ __launch_bounds__(512) void blob_finalize_kernel(
    const float* __restrict__ partials, float* __restrict__ out)
{
    __shared__ double totals[NACC * BATCH];   // index p = j*BATCH + b
    const int lane = threadIdx.x & 63;
    const int wave = threadIdx.x >> 6;        // 8 waves

    for (int p = wave; p < NACC * BATCH; p += 8) {
        double s = 0.0;
#pragma unroll
        for (int i = 0; i < BLOCKS_X / 64; ++i)        // 5 loads
            s += (double)partials[(size_t)p * BLOCKS_X + lane + i * 64];
        for (int off = 32; off > 0; off >>= 1) s += __shfl_down(s, off, 64);
        if (lane == 0) totals[p] = s;
    }
    __syncthreads();

    if (threadIdx.x == 0) {
        const double Vd = (double)VOX;
        const double TA = 0.3, TB = 0.7;
        double sum_main = 0.0, sum_blob = 0.0;
        for (int b = 0; b < BATCH; ++b) {
            const double S0 = totals[0 * BATCH + b];
            const double A  = totals[1 * BATCH + b];
            const double n0 = totals[2 * BATCH + b];
            // main Tversky, class 0
            {
                double tp = A, fp = S0 - A, fn = n0 - A;
                sum_main += tp / fmax(tp + TA * fp + TB * fn, 1e-8);
            }
            // main Tversky, class 1
            {
                double tp = (Vd - n0) - (S0 - A);
                double fp = (Vd - S0) - tp;
                double fn = (Vd - n0) - tp;
                sum_main += tp / fmax(tp + TA * fp + TB * fn, 1e-8);
            }
            for (int k = 0; k < 8; ++k) {
                const double P0 = totals[(3 + k) * BATCH + b];
                const double Nl = totals[(11 + k) * BATCH + b];
                const double P1 = Nl - P0;
                const double m  = Vd - n0 - Nl;  // voxels of OTHER blobs -> p=(.5,.5)
                // class 0: g = (L != lab)
                {
                    double tp = A + 0.5 * m;
                    double fp = P0;
                    double fn = (Vd - Nl) - tp;
                    sum_blob += tp / fmax(tp + TA * fp + TB * fn, 1e-8);
                }
                // class 1: g = (L == lab)
                {
                    double tp = P1;
                    double fp = (n0 - A) + 0.5 * m;
                    double fn = P0;
                    sum_blob += tp / fmax(tp + TA * fp + TB * fn, 1e-8);
                }
            }
        }
        // loss = MAIN_W*CRIT_W*main_loss + blob_loss
        //      = -(sum_main / (B*C)) - (0.25/(K*B)) * sum_blob
        out[0] = (float)(-(sum_main / 8.0 + sum_blob / 128.0));
    }
}

extern "C" void kernel_launch(void* const* d_in, const int* in_sizes, int n_in,
                              void* d_out, int out_size, void* d_ws, size_t ws_size,
                              hipStream_t stream) {
    const float* x  = (const float*)d_in[0];
    const int*   ml = (const int*)d_in[1];
    float* out      = (float*)d_out;
    float* partials = (float*)d_ws;   // NACC*BATCH*BLOCKS_X floats = 95 KiB

    dim3 grid(BLOCKS_X, BATCH);
    blob_reduce_kernel<<<grid, THREADS, 0, stream>>>(x, ml, partials);
    blob_finalize_kernel<<<1, 512, 0, stream>>>(partials, out);
}

// Round 3
// 113.776 us; speedup vs baseline: 1.7087x; 1.0117x over previous
//
#include <hip/hip_runtime.h>

#define BATCH 4
#define NCLS 2
#define VOX 1638400            // 64*160*160
#define VOX4 (VOX / 4)
#define BLOCKS_X 320           // 320*256 threads/batch -> exactly 5 iters/thread
#define THREADS 256
#define ITERS (VOX4 / (BLOCKS_X * THREADS))   // = 5, compile-time
#define NACC 19                // S0, A, n0, P[1..8], N[1..8]

// ---------------------------------------------------------------------------
// Kernel 1: per-(sample, block) partial reductions.
// VALU-bound fix (round-3): labels are large boxes, so most 256-voxel wave
// spans have ONE uniform label. Fast path: readfirstlane + __all check, then
// scalar-branched compile-time accumulator update (~26 VALU/iter). Mixed
// waves use the original predicated 8-label loop (~220 VALU/iter).
// partials layout: [(j*BATCH+b)*BLOCKS_X + bx] for coalesced finalize reads.
// NOTE: no device-scope fences/atomics (round-1: agent-scope release/acquire
// in-kernel cost ~90 µs in L2 writeback storms).
// ---------------------------------------------------------------------------
__global__ __launch_bounds__(THREADS, 5) void blob_reduce_kernel(
    const float* __restrict__ x, const int* __restrict__ ml,
    float* __restrict__ partials)
{
    const int b = blockIdx.y;
    const float4* __restrict__ x0v = (const float4*)(x + (size_t)b * NCLS * VOX);
    const float4* __restrict__ x1v = (const float4*)(x + (size_t)b * NCLS * VOX + VOX);
    const int4*   __restrict__ mlv = (const int4*)(ml + (size_t)b * VOX);

    float acc[NACC];
#pragma unroll
    for (int j = 0; j < NACC; ++j) acc[j] = 0.f;

    const int tid = blockIdx.x * THREADS + threadIdx.x;   // 0..81919
    const int stride = BLOCKS_X * THREADS;                // 81920

#pragma unroll
    for (int it = 0; it < ITERS; ++it) {
        const int i = tid + it * stride;
        float4 a0 = x0v[i];
        float4 a1 = x1v[i];
        int4   m  = mlv[i];
        // softmax over 2 classes: p0 = 1/(1+exp(x1-x0)) — bitwise identical
        // on both paths below (only summation ORDER differs).
        float p00 = 1.0f / (1.0f + __expf(a1.x - a0.x));
        float p01 = 1.0f / (1.0f + __expf(a1.y - a0.y));
        float p02 = 1.0f / (1.0f + __expf(a1.z - a0.z));
        float p03 = 1.0f / (1.0f + __expf(a1.w - a0.w));
        float s4 = (p00 + p01) + (p02 + p03);
        acc[0] += s4;                                     // S0

        const int Lu = __builtin_amdgcn_readfirstlane(m.x);
        const bool same = (m.x == Lu) & (m.y == Lu) & (m.z == Lu) & (m.w == Lu);
        if (__all(same)) {
            // wave-uniform label Lu: scalar branch tree, compile-time indices
            if (Lu == 0)      { acc[1]  += s4; acc[2]  += 4.f; }
            else if (Lu == 1) { acc[3]  += s4; acc[11] += 4.f; }
            else if (Lu == 2) { acc[4]  += s4; acc[12] += 4.f; }
            else if (Lu == 3) { acc[5]  += s4; acc[13] += 4.f; }
            else if (Lu == 4) { acc[6]  += s4; acc[14] += 4.f; }
            else if (Lu == 5) { acc[7]  += s4; acc[15] += 4.f; }
            else if (Lu == 6) { acc[8]  += s4; acc[16] += 4.f; }
            else if (Lu == 7) { acc[9]  += s4; acc[17] += 4.f; }
            else              { acc[10] += s4; acc[18] += 4.f; }
        } else {
            // mixed wave: original exact predicated path
            float ps[4] = {p00, p01, p02, p03};
            int   ls[4] = {m.x, m.y, m.z, m.w};
#pragma unroll
            for (int e = 0; e < 4; ++e) {
                float p = ps[e];
                int L = ls[e];
                bool z = (L == 0);
                acc[1] += z ? p : 0.f;             // A
                acc[2] += z ? 1.f : 0.f;           // n0
#pragma unroll
                for (int l = 0; l < 8; ++l) {
                    bool eq = (L == l + 1);
                    acc[3 + l]  += eq ? p : 0.f;   // P_l
                    acc[11 + l] += eq ? 1.f : 0.f; // N_l
                }
            }
        }
    }

    // block reduce: wave shuffle (64 lanes) -> LDS across 4 waves
    __shared__ float red[4][NACC];
    const int lane = threadIdx.x & 63;
    const int wave = threadIdx.x >> 6;
#pragma unroll
    for (int j = 0; j < NACC; ++j) {
        float v = acc[j];
        for (int off = 32; off > 0; off >>= 1) v += __shfl_down(v, off, 64);
        if (lane == 0) red[wave][j] = v;
    }
    __syncthreads();
    if (threadIdx.x < NACC) {
        float s = red[0][threadIdx.x] + red[1][threadIdx.x] +
                  red[2][threadIdx.x] + red[3][threadIdx.x];
        partials[((size_t)threadIdx.x * BATCH + b) * BLOCKS_X + blockIdx.x] = s;
    }
}

// ---------------------------------------------------------------------------
// Kernel 2: reduce 320 partials per (j,b) in double, then closed-form loss.
// ---------------------------------------------------------------------------
__global__ __launch_bounds__(512) void blob_finalize_kernel(
    const float* __restrict__ partials, float* __restrict__ out)
{
    __shared__ double totals[NACC * BATCH];   // index p = j*BATCH + b
    const int lane = threadIdx.x & 63;
    const int wave = threadIdx.x >> 6;        // 8 waves

    for (int p = wave; p < NACC * BATCH; p += 8) {
        double s = 0.0;
#pragma unroll
        for (int i = 0; i < BLOCKS_X / 64; ++i)        // 5 loads
            s += (double)partials[(size_t)p * BLOCKS_X + lane + i * 64];
        for (int off = 32; off > 0; off >>= 1) s += __shfl_down(s, off, 64);
        if (lane == 0) totals[p] = s;
    }
    __syncthreads();

    if (threadIdx.x == 0) {
        const double Vd = (double)VOX;
        const double TA = 0.3, TB = 0.7;
        double sum_main = 0.0, sum_blob = 0.0;
        for (int b = 0; b < BATCH; ++b) {
            const double S0 = totals[0 * BATCH + b];
            const double A  = totals[1 * BATCH + b];
            const double n0 = totals[2 * BATCH + b];
            // main Tversky, class 0
            {
                double tp = A, fp = S0 - A, fn = n0 - A;
                sum_main += tp / fmax(tp + TA * fp + TB * fn, 1e-8);
            }
            // main Tversky, class 1
            {
                double tp = (Vd - n0) - (S0 - A);
                double fp = (Vd - S0) - tp;
                double fn = (Vd - n0) - tp;
                sum_main += tp / fmax(tp + TA * fp + TB * fn, 1e-8);
            }
            for (int k = 0; k < 8; ++k) {
                const double P0 = totals[(3 + k) * BATCH + b];
                const double Nl = totals[(11 + k) * BATCH + b];
                const double P1 = Nl - P0;
                const double m  = Vd - n0 - Nl;  // voxels of OTHER blobs -> p=(.5,.5)
                // class 0: g = (L != lab)
                {
                    double tp = A + 0.5 * m;
                    double fp = P0;
                    double fn = (Vd - Nl) - tp;
                    sum_blob += tp / fmax(tp + TA * fp + TB * fn, 1e-8);
                }
                // class 1: g = (L == lab)
                {
                    double tp = P1;
                    double fp = (n0 - A) + 0.5 * m;
                    double fn = P0;
                    sum_blob += tp / fmax(tp + TA * fp + TB * fn, 1e-8);
                }
            }
        }
        // loss = MAIN_W*CRIT_W*main_loss + blob_loss
        //      = -(sum_main / (B*C)) - (0.25/(K*B)) * sum_blob
        out[0] = (float)(-(sum_main / 8.0 + sum_blob / 128.0));
    }
}

extern "C" void kernel_launch(void* const* d_in, const int* in_sizes, int n_in,
                              void* d_out, int out_size, void* d_ws, size_t ws_size,
                              hipStream_t stream) {
    const float* x  = (const float*)d_in[0];
    const int*   ml = (const int*)d_in[1];
    float* out      = (float*)d_out;
    float* partials = (float*)d_ws;   // NACC*BATCH*BLOCKS_X floats = 95 KiB

    dim3 grid(BLOCKS_X, BATCH);
    blob_reduce_kernel<<<grid, THREADS, 0, stream>>>(x, ml, partials);
    blob_finalize_kernel<<<1, 512, 0, stream>>>(partials, out);
}